// Round 1
// 442.606 us; speedup vs baseline: 1.2775x; 1.2775x over previous
//
#include <hip/hip_runtime.h>
#include <math.h>

// Cyborg stack machine: B=256, S=128, V=512, H=30, N_STACKS=2, R=2, DEPTH=4
// All stack/peek/output vectors live in span{ones, init_vec, syms0..29} (32-dim).
// kC (R5 redesign): 4 waves/block, ONE ROW PER THREAD. Stack state replicated in
// all 4 waves; peek/Gram computed once per step. 4 barriers/step.
// kA (R6 redesign): split-f16 MFMA GEMM. x = xh + xl, w = wh + wl (f16 hi/lo);
// acc = xh*wh + xh*wl + xl*wh in fp32 via mfma_f32_16x16x32_f16 — fp32-grade
// precision (missing xl*wl term ~1e-6 rel) at ~13x the fp32 vector rate.

#define SS 128
#define VV 512
#define NROWS 208      // 8 pop + 8 pushop + 128 pushfn + 64 calc
#define ZOFF 1e-6f

// ws layout (float offsets)
#define OFF_I0   0                          // interp0: 32768*208
#define OFF_OC   (32768*208)                // out coords: 32768*32
#define OFF_GI   (OFF_OC + 32768*32)        // G[2][32][208]  (stack, basis, row)
#define OFF_M    (OFF_GI + 2*32*208)        // Gram 32*32
#define OFF_A    (OFF_M + 1024)             // A coef 208*3
#define OFF_Bc   (OFF_A + 624)              // B coef 208*3
#define OFF_W0   (OFF_Bc + 624)             // Wh/Wl f16: 2 x [208][512] halves (= old W0 f32 footprint)

typedef _Float16 half8 __attribute__((ext_vector_type(8)));
typedef float f32x4 __attribute__((ext_vector_type(4)));

__device__ __forceinline__ const float* w_row(int r, const float* pw, const float* pow_,
                                              const float* pfw, const float* cw) {
    if (r < 8)   return pw   + r * 1536;
    if (r < 16)  return pow_ + (r - 8) * 1536;
    if (r < 144) return pfw  + (r - 16) * 1536;
    return cw + (r - 144) * 1536;
}
__device__ __forceinline__ const float* nw_row(int r, const float* pn, const float* pon,
                                               const float* pfn, const float* cn) {
    if (r < 8)   return pn   + r * 3;
    if (r < 16)  return pon  + (r - 8) * 3;
    if (r < 144) return pfn  + (r - 16) * 3;
    return cn + (r - 144) * 3;
}

// ---------------- kernel B: precompute tables ----------------
__global__ void kB(const float* __restrict__ syms, const float* __restrict__ siv,
                   const float* __restrict__ pw, const float* __restrict__ pn,
                   const float* __restrict__ pow_, const float* __restrict__ pon,
                   const float* __restrict__ pfw, const float* __restrict__ pfn,
                   const float* __restrict__ cw, const float* __restrict__ cn,
                   float* __restrict__ ws) {
    int blk = blockIdx.x, tid = threadIdx.x;
    if (blk < 64) {
        // G[jj][e][c] = basis_e . w_row(c)[(jj+1)*512 ..)
        int jj = blk >> 5, e = blk & 31;
        __shared__ float bas[512];
        for (int i = tid; i < 512; i += 256)
            bas[i] = (e == 0) ? 1.0f : ((e == 1) ? siv[i] : syms[(e - 2) * 512 + i]);
        __syncthreads();
        if (tid < NROWS) {
            int c = tid;
            const float4* w4 = (const float4*)(w_row(c, pw, pow_, pfw, cw) + (jj + 1) * 512);
            const float4* b4 = (const float4*)bas;
            float s = 0.f;
            for (int q = 0; q < 128; ++q) {
                float4 a = b4[q], b = w4[q];
                s += a.x * b.x + a.y * b.y + a.z * b.z + a.w * b.w;
            }
            ws[OFF_GI + (jj * 32 + e) * 208 + c] = s;
        }
    } else if (blk == 64) {
        // Gram M[m][mm]
        __shared__ float basw[32 * 512];
        for (int i = tid; i < 32 * 512; i += 256) {
            int m = i >> 9, v = i & 511;
            basw[i] = (m == 0) ? 1.0f : ((m == 1) ? siv[v] : syms[(m - 2) * 512 + v]);
        }
        __syncthreads();
        for (int p = tid; p < 1024; p += 256) {
            int m = p >> 5, mm = p & 31;
            const float4* a4 = (const float4*)(basw + m * 512);
            const float4* b4 = (const float4*)(basw + mm * 512);
            float s = 0.f;
            for (int q = 0; q < 128; ++q) {
                float4 a = a4[q], b = b4[q];
                s += a.x * b.x + a.y * b.y + a.z * b.z + a.w * b.w;
            }
            ws[OFF_M + p] = s;
        }
    } else if (blk == 65) {
        // folded NAND coefs: A=(2*sig-1)/||w||, B=1-sig   for (r, j)
        for (int idx = tid; idx < 624; idx += 256) {
            int r = idx / 3, j = idx % 3;
            const float4* w4 = (const float4*)(w_row(r, pw, pow_, pfw, cw) + j * 512);
            float s = 0.f;
            for (int q = 0; q < 128; ++q) {
                float4 b = w4[q];
                s += b.x * b.x + b.y * b.y + b.z * b.z + b.w * b.w;
            }
            float nrm = fmaxf(sqrtf(s), 1e-8f);
            float nwv = nw_row(r, pn, pon, pfn, cn)[j];
            float sig = 1.f / (1.f + expf(-nwv));
            ws[OFF_A + idx]  = (2.f * sig - 1.f) / nrm;
            ws[OFF_Bc + idx] = 1.f - sig;
        }
    } else {
        // gather w j=0 slice as split-f16 hi/lo: Wh/Wl [208][512] halves — 16 blocks
        int part = blk - 66;
        _Float16* whp = (_Float16*)(ws + OFF_W0);
        _Float16* wlp = whp + 208 * 512;
        for (int i = tid; i < 6656; i += 256) {
            int flat = part * 6656 + i;
            int c = flat >> 9, v = flat & 511;
            float wv = w_row(c, pw, pow_, pfw, cw)[v];
            _Float16 h = (_Float16)wv;
            whp[flat] = h;
            wlp[flat] = (_Float16)(wv - (float)h);
        }
    }
}

// ---------------- kernel A: interp0 via split-f16 MFMA GEMM ----------------
// Block = 64 rows x 208 cols, K=512 in 16 steps of 32. 4 waves split the 13
// col-tiles {4,3,3,3}. x staged f32->f16h/l in LDS in MFMA-fragment order
// (conflict-free b128), double-buffered, 1 barrier/step. B frags from L2.
// ||x||^2 accumulated during staging (no separate norm pass).
__global__ __launch_bounds__(256) void kA(const float* __restrict__ x, float* __restrict__ ws) {
    __shared__ half8 AH[2][256];   // [buf][mfrag*64 + fraglane]
    __shared__ half8 AL[2][256];
    __shared__ float red[256];
    __shared__ float invx[64];
    const int tid = threadIdx.x;
    const int wid = tid >> 6, l = tid & 63;
    const size_t bt0 = (size_t)blockIdx.x * 64;

    // staging role: thread covers row sr (always), k-segment ss*8 within each 32-tile
    const int sr = tid >> 2, ss = tid & 3;
    const float* xp = x + (bt0 + sr) * 512 + ss * 8;
    const int wpos = (sr >> 4) * 64 + (sr & 15) + (ss << 4);   // frag slot

    const _Float16* whp = (const _Float16*)(ws + OFF_W0);
    const _Float16* wlp = whp + 208 * 512;

    // col-tile split over waves: {4,3,3,3}
    const int t0 = (wid == 0) ? 0 : (1 + 3 * wid);   // 0,4,7,10
    const int nt = (wid == 0) ? 4 : 3;

    f32x4 acc[4][4];
#pragma unroll
    for (int m = 0; m < 4; ++m)
#pragma unroll
        for (int tt = 0; tt < 4; ++tt)
            acc[m][tt] = (f32x4){0.f, 0.f, 0.f, 0.f};

    float sumsq = 0.f;
    auto stage = [&](int kt, int buf) {
        float v[8];
        *(float4*)v       = *(const float4*)(xp + kt * 32);
        *(float4*)(v + 4) = *(const float4*)(xp + kt * 32 + 4);
        half8 hh, hl;
#pragma unroll
        for (int j = 0; j < 8; ++j) {
            sumsq += v[j] * v[j];
            _Float16 h = (_Float16)v[j];
            hh[j] = h;
            hl[j] = (_Float16)(v[j] - (float)h);
        }
        AH[buf][wpos] = hh;
        AL[buf][wpos] = hl;
    };

    stage(0, 0);
    __syncthreads();

    for (int kt = 0; kt < 16; ++kt) {
        const int buf = kt & 1;
        if (kt < 15) stage(kt + 1, buf ^ 1);

        half8 ahm[4], alm[4];
#pragma unroll
        for (int m = 0; m < 4; ++m) {
            ahm[m] = AH[buf][m * 64 + l];
            alm[m] = AL[buf][m * 64 + l];
        }
        const int kof = kt * 32 + (l >> 4) * 8;
#pragma unroll
        for (int tt = 0; tt < 4; ++tt) {
            if (tt < nt) {
                const int c = (t0 + tt) * 16 + (l & 15);
                half8 bh = *(const half8*)(whp + c * 512 + kof);
                half8 bl = *(const half8*)(wlp + c * 512 + kof);
#pragma unroll
                for (int m = 0; m < 4; ++m) {
                    acc[m][tt] = __builtin_amdgcn_mfma_f32_16x16x32_f16(ahm[m], bh, acc[m][tt], 0, 0, 0);
                    acc[m][tt] = __builtin_amdgcn_mfma_f32_16x16x32_f16(ahm[m], bl, acc[m][tt], 0, 0, 0);
                    acc[m][tt] = __builtin_amdgcn_mfma_f32_16x16x32_f16(alm[m], bh, acc[m][tt], 0, 0, 0);
                }
            }
        }
        __syncthreads();
    }

    // row inverse norms (4 partials per row, rows = tid>>2 mapping)
    red[tid] = sumsq;
    __syncthreads();
    if (tid < 64) {
        float s = red[tid * 4] + red[tid * 4 + 1] + red[tid * 4 + 2] + red[tid * 4 + 3];
        invx[tid] = 1.f / fmaxf(sqrtf(s), 1e-8f);
    }
    __syncthreads();

    // epilogue: interp0 = A0*|dot|*invx + B0.  D frag: col=lane&15, row=(lane>>4)*4+reg
#pragma unroll
    for (int tt = 0; tt < 4; ++tt) {
        if (tt < nt) {
            const int c = (t0 + tt) * 16 + (l & 15);
            const float A0 = ws[OFF_A + c * 3];
            const float B0 = ws[OFF_Bc + c * 3];
#pragma unroll
            for (int m = 0; m < 4; ++m) {
                const int rbase = m * 16 + (l >> 4) * 4;
#pragma unroll
                for (int j = 0; j < 4; ++j) {
                    const float ix = invx[rbase + j];
                    ws[OFF_I0 + (bt0 + rbase + j) * 208 + c] = A0 * fabsf(acc[m][tt][j]) * ix + B0;
                }
            }
        }
    }
}

// ---------------- kernel C: 4 waves/block, one row per thread ----------------
// tid 0..143:   phase-1 row tid (G1[64] in regs)
// wave3 (192..255): calc row 144+(tid&63) (G2[64])
// wave1 (64..127):  Gram duty (Mr[32])
// All 4 waves replicate stack state (lane l=tid&63: k=l>>5, m=l&31).
__global__ __attribute__((amdgpu_flat_work_group_size(256, 256), amdgpu_waves_per_eu(1, 1)))
void kC(float* __restrict__ ws, const float* __restrict__ sharp) {
    __shared__ float pkL[64];
    __shared__ float nndL[144];
    __shared__ float nnd2L[64];
    __shared__ float iqL[2];
    const int b = blockIdx.x, tid = threadIdx.x;
    const int wid = tid >> 6, l = tid & 63;
    const int k = l >> 5, m = l & 31;
    const int isRow = (tid < 144);
    const int r2 = 144 + l;            // wave3's calc row

    const float* GI = ws + OFF_GI;
    // per-role register tables
    float G1[64], G2[64];
    float4 Mr[8];
    float A1r = 0.f, A2r = 0.f, B1r = 0.f, B2r = 0.f;
    float A1d = 0.f, A2d = 0.f, B1d = 0.f, B2d = 0.f;
    if (isRow) {
#pragma unroll
        for (int i = 0; i < 32; ++i) {
            G1[i]      = GI[i * 208 + tid];
            G1[32 + i] = GI[(32 + i) * 208 + tid];
        }
        A1r = ws[OFF_A + tid * 3 + 1];  A2r = ws[OFF_A + tid * 3 + 2];
        B1r = ws[OFF_Bc + tid * 3 + 1]; B2r = ws[OFF_Bc + tid * 3 + 2];
    }
    if (wid == 3) {
#pragma unroll
        for (int i = 0; i < 32; ++i) {
            G2[i]      = GI[i * 208 + r2];
            G2[32 + i] = GI[(32 + i) * 208 + r2];
        }
        A1d = ws[OFF_A + r2 * 3 + 1];  A2d = ws[OFF_A + r2 * 3 + 2];
        B1d = ws[OFF_Bc + r2 * 3 + 1]; B2d = ws[OFF_Bc + r2 * 3 + 2];
    }
    if (wid == 1) {
#pragma unroll
        for (int q = 0; q < 8; ++q) Mr[q] = *(const float4*)(ws + OFF_M + m * 32 + q * 4);
    }
    const float sh = sharp[k];

    // replicated stack state
    float st[4], p[4];
#pragma unroll
    for (int d = 0; d < 4; ++d) {
        st[d] = (d == 1) ? ((m == 1) ? 1.f : 0.f) : ((m == 0) ? ZOFF : 0.f);
        p[d] = (d == 1) ? 1.f : 0.f;
    }
    float pk = st[0] * p[0] + st[1] * p[1] + st[2] * p[2] + st[3] * p[3];

    const float* i0base = ws + OFF_I0 + (size_t)b * SS * 208;
    float i0r = isRow ? i0base[tid] : 0.f;
    float i0d = (wid == 3) ? i0base[r2] : 0.f;

    // pre-loop: publish pk, Gram(pk) -> iq
    if (wid == 0) pkL[l] = pk;
    __syncthreads();
    if (wid == 1) {
        const float* ph = pkL + 32 * k;
        float Mv = 0.f;
#pragma unroll
        for (int q = 0; q < 8; ++q) {
            float4 mr = Mr[q];
            float4 a = *(const float4*)(ph + 4 * q);
            Mv += mr.x * a.x + mr.y * a.y + mr.z * a.z + mr.w * a.w;
        }
        float part = pk * Mv;
        part += __shfl_xor(part, 1);  part += __shfl_xor(part, 2);
        part += __shfl_xor(part, 4);  part += __shfl_xor(part, 8);
        part += __shfl_xor(part, 16);
        if ((tid & 31) == 0) iqL[k] = 1.f / fmaxf(sqrtf(part), 1e-8f);
    }
    __syncthreads();
    float iq0 = iqL[0], iq1 = iqL[1];

    for (int t = 0; t < SS; ++t) {
        const int tn = (t < SS - 1) ? (t + 1) : t;
        // ---- region A: phase-1 NAND rows ----
        float i0n = 0.f;
        if (isRow) {
            i0n = i0base[(size_t)tn * 208 + tid];
            float d1 = 0.f, d2 = 0.f;
#pragma unroll
            for (int q = 0; q < 8; ++q) {
                float4 a = *(const float4*)(pkL + 4 * q);
                float4 c = *(const float4*)(pkL + 32 + 4 * q);
                d1 += a.x * G1[4*q] + a.y * G1[4*q+1] + a.z * G1[4*q+2] + a.w * G1[4*q+3];
                d2 += c.x * G1[32+4*q] + c.y * G1[33+4*q] + c.z * G1[34+4*q] + c.w * G1[35+4*q];
            }
            nndL[tid] = i0r * (A1r * fabsf(d1) * iq0 + B1r) * (A2r * fabsf(d2) * iq1 + B2r);
        }
        __syncthreads();   // B1: nndL visible

        // ---- region B: gates + push_val + state update (replicated in all waves) ----
        float4 gp4 = *(const float4*)(nndL + 4 * k);
        float4 gq4 = *(const float4*)(nndL + 8 + 4 * k);
        float prp0 = 1.f / (1.f + __expf((fmaxf(gp4.z, gp4.w) - fmaxf(gp4.x, gp4.y)) * sh));
        float prq0 = 1.f / (1.f + __expf((fmaxf(gq4.z, gq4.w) - fmaxf(gq4.x, gq4.y)) * sh));
        float prp1 = 1.f - prp0, prq1 = 1.f - prq0;
        float prx = 0.f, pry = 0.f;
        if (m >= 2) {
            float2 pr2 = *(const float2*)(nndL + 16 + 64 * k + 2 * m - 4);
            prx = pr2.x; pry = pr2.y;
        }
        float4 t30 = *(const float4*)(nndL + 16 + 64 * k + 60);
        float pkOther = __shfl_xor(pk, 32);
        float pk0m = k ? pkOther : pk;
        float pk1m = k ? pk : pkOther;
        float pvc = prx + pry + (t30.x + t30.y) * pk0m + (t30.z + t30.w) * pk1m;

        float zc = (m == 0) ? ZOFF : 0.f;
        float s1[4], p1[4];
#pragma unroll
        for (int d = 0; d < 4; ++d) {
            float ps = st[d] * (1.f - p[d]) + zc * p[d];
            s1[d] = ps * prp0 + st[d] * prp1;
            p1[d] = p[(d + 1) & 3] * prp0 + p[d] * prp1;
        }
#pragma unroll
        for (int d = 0; d < 4; ++d) {
            float pu = p1[(d + 3) & 3];
            float su = s1[d] * (1.f - pu) + pvc * pu;
            st[d] = su * prq0 + s1[d] * prq1;
            p[d] = pu * prq0 + p1[d] * prq1;
        }
        float pkp = st[0] * p[0] + st[1] * p[1] + st[2] * p[2] + st[3] * p[3];
        if (wid == 0) pkL[l] = pkp;
        __syncthreads();   // B2: pkL' visible

        // ---- region C: calc dots (wave3) + Gram(pk') (wave1) ----
        float dd1 = 0.f, dd2 = 0.f, i0dn = 0.f;
        if (wid == 3) {
            i0dn = i0base[(size_t)tn * 208 + r2];
#pragma unroll
            for (int q = 0; q < 8; ++q) {
                float4 a = *(const float4*)(pkL + 4 * q);
                float4 c = *(const float4*)(pkL + 32 + 4 * q);
                dd1 += a.x * G2[4*q] + a.y * G2[4*q+1] + a.z * G2[4*q+2] + a.w * G2[4*q+3];
                dd2 += c.x * G2[32+4*q] + c.y * G2[33+4*q] + c.z * G2[34+4*q] + c.w * G2[35+4*q];
            }
        } else if (wid == 1) {
            const float* ph = pkL + 32 * k;
            float Mv = 0.f;
#pragma unroll
            for (int q = 0; q < 8; ++q) {
                float4 mr = Mr[q];
                float4 a = *(const float4*)(ph + 4 * q);
                Mv += mr.x * a.x + mr.y * a.y + mr.z * a.z + mr.w * a.w;
            }
            float part = pkp * Mv;
            part += __shfl_xor(part, 1);  part += __shfl_xor(part, 2);
            part += __shfl_xor(part, 4);  part += __shfl_xor(part, 8);
            part += __shfl_xor(part, 16);
            if ((tid & 31) == 0) iqL[k] = 1.f / fmaxf(sqrtf(part), 1e-8f);
        }
        __syncthreads();   // B3: iqL' visible

        // ---- region D: calc nnd (wave3); all refresh iq regs ----
        iq0 = iqL[0]; iq1 = iqL[1];
        if (wid == 3) {
            nnd2L[l] = i0d * (A1d * fabsf(dd1) * iq0 + B1d) * (A2d * fabsf(dd2) * iq1 + B2d);
            i0d = i0dn;
        }
        __syncthreads();   // B4: nnd2L visible

        // ---- region E: output coords (wave0 lanes < 32) ----
        float pkpOther = __shfl_xor(pkp, 32);
        if (tid < 32) {
            float cx = 0.f, cy = 0.f;
            if (m >= 2) {
                float2 c2 = *(const float2*)(nnd2L + 2 * m - 4);
                cx = c2.x; cy = c2.y;
            }
            float4 c30 = *(const float4*)(nnd2L + 60);
            float oc = cx + cy + (c30.x + c30.y) * pkp + (c30.z + c30.w) * pkpOther;
            ws[OFF_OC + ((size_t)b * SS + t) * 32 + m] = oc;
        }
        pk = pkp;
        i0r = i0n;
    }
}

// ---------------- kernel D: expand coords -> 512-dim output (barrier-free) ----------------
__global__ __launch_bounds__(256) void kD(const float* __restrict__ ws, const float* __restrict__ syms,
                                          const float* __restrict__ siv, float* __restrict__ out) {
    int t = threadIdx.x;
    int rg = t >> 6;
    int vc = (t & 63) * 8;
    size_t r0 = (size_t)blockIdx.x * 16 + rg * 4;
    const float* oc = ws + OFF_OC;
    float acc[4][8];
    float4 sv0 = *(const float4*)(siv + vc);
    float4 sv1 = *(const float4*)(siv + vc + 4);
#pragma unroll
    for (int rr = 0; rr < 4; ++rr) {
        float c0 = oc[(r0 + rr) * 32 + 0];
        float c1 = oc[(r0 + rr) * 32 + 1];
        acc[rr][0] = c0 + c1 * sv0.x; acc[rr][1] = c0 + c1 * sv0.y;
        acc[rr][2] = c0 + c1 * sv0.z; acc[rr][3] = c0 + c1 * sv0.w;
        acc[rr][4] = c0 + c1 * sv1.x; acc[rr][5] = c0 + c1 * sv1.y;
        acc[rr][6] = c0 + c1 * sv1.z; acc[rr][7] = c0 + c1 * sv1.w;
    }
    for (int mm = 0; mm < 30; ++mm) {
        float4 b0 = *(const float4*)(syms + mm * 512 + vc);
        float4 b1 = *(const float4*)(syms + mm * 512 + vc + 4);
#pragma unroll
        for (int rr = 0; rr < 4; ++rr) {
            float c = oc[(r0 + rr) * 32 + 2 + mm];
            acc[rr][0] += c * b0.x; acc[rr][1] += c * b0.y;
            acc[rr][2] += c * b0.z; acc[rr][3] += c * b0.w;
            acc[rr][4] += c * b1.x; acc[rr][5] += c * b1.y;
            acc[rr][6] += c * b1.z; acc[rr][7] += c * b1.w;
        }
    }
#pragma unroll
    for (int rr = 0; rr < 4; ++rr) {
        float* o = out + (r0 + rr) * 512 + vc;
        *(float4*)o       = make_float4(acc[rr][0], acc[rr][1], acc[rr][2], acc[rr][3]);
        *(float4*)(o + 4) = make_float4(acc[rr][4], acc[rr][5], acc[rr][6], acc[rr][7]);
    }
}

extern "C" void kernel_launch(void* const* d_in, const int* in_sizes, int n_in,
                              void* d_out, int out_size, void* d_ws, size_t ws_size,
                              hipStream_t stream) {
    const float* x    = (const float*)d_in[0];
    const float* syms = (const float*)d_in[1];
    const float* siv  = (const float*)d_in[2];
    const float* shp  = (const float*)d_in[3];
    const float* pw   = (const float*)d_in[4];
    const float* pn   = (const float*)d_in[5];
    const float* pow_ = (const float*)d_in[6];
    const float* pon  = (const float*)d_in[7];
    const float* pfw  = (const float*)d_in[8];
    const float* pfn  = (const float*)d_in[9];
    const float* cw   = (const float*)d_in[10];
    const float* cn   = (const float*)d_in[11];
    float* ws  = (float*)d_ws;
    float* out = (float*)d_out;

    hipLaunchKernelGGL(kB, dim3(82),   dim3(256), 0, stream,
                       syms, siv, pw, pn, pow_, pon, pfw, pfn, cw, cn, ws);
    hipLaunchKernelGGL(kA, dim3(512),  dim3(256), 0, stream, x, ws);
    hipLaunchKernelGGL(kC, dim3(256),  dim3(256), 0, stream, ws, shp);
    hipLaunchKernelGGL(kD, dim3(2048), dim3(256), 0, stream, ws, syms, siv, out);
}